// Round 13
// baseline (28737.723 us; speedup 1.0000x reference)
//
#include <hip/hip_runtime.h>
#include <hip/hip_bf16.h>

#define NTOK 32768   // input rows
#define KEMB 8192    // embedding codes
#define DIM  256     // feature dim
#define EPSM 1e-3f   // gate margin: worst-case |s_hat - np_dd| ~1.8e-4 incl key trunc

typedef __attribute__((ext_vector_type(8))) short bf16x8;
typedef __attribute__((ext_vector_type(4))) float f32x4;
typedef __attribute__((ext_vector_type(8))) unsigned short ushort8;

typedef __attribute__((address_space(3))) void as3_void;
typedef __attribute__((address_space(1))) const void as1_cvoid;

__device__ __forceinline__ unsigned short f2bf(float f) {
  unsigned int u = __float_as_uint(f);
  unsigned int r = (u + 0x7FFFu + ((u >> 16) & 1u)) >> 16;
  return (unsigned short)r;
}

__device__ __forceinline__ unsigned umin2(unsigned a, unsigned b) { return a < b ? a : b; }
__device__ __forceinline__ unsigned umax2(unsigned a, unsigned b) { return a > b ? a : b; }

// biased-key scheme: all scores stored as (score + 1.0) > 0, so the raw fp32
// bit pattern is order-preserving. Low 7 bits carry the block-local index.
__device__ __forceinline__ float key2f(unsigned k) {
  return __uint_as_float(k & 0xFFFFFF80u) - 1.0f;
}

// ---------------- prep: fp32 -> bf16 copies ----------------
__global__ __launch_bounds__(256) void cast_bf16_k(const float* __restrict__ src,
                                                   unsigned short* __restrict__ dst,
                                                   int n8) {
  int i = blockIdx.x * 256 + threadIdx.x;
  if (i >= n8) return;
  const float4* s4 = (const float4*)src;
  float4 a = s4[2 * i], b = s4[2 * i + 1];
  ushort8 r;
  r[0] = f2bf(a.x); r[1] = f2bf(a.y); r[2] = f2bf(a.z); r[3] = f2bf(a.w);
  r[4] = f2bf(b.x); r[5] = f2bf(b.y); r[6] = f2bf(b.z); r[7] = f2bf(b.w);
  ((ushort8*)dst)[i] = r;
}

// ---------------- numpy-pairwise fp32 row sum of squares (validated r8) ------
__global__ __launch_bounds__(256) void rowsq_np(const float* __restrict__ src,
                                                float* __restrict__ dst,
                                                int nrows) {
  int g = (blockIdx.x * 256 + threadIdx.x) >> 4;   // row id
  if (g >= nrows) return;
  int l = threadIdx.x & 15;
  int j = l & 7, half = l >> 3;
  const float* row = src + (size_t)g * DIM + half * 128 + j;
  float s = 0.f;
  #pragma unroll
  for (int i = 0; i < 16; ++i) {
    float v = row[8 * i];
    s = __fadd_rn(s, __fmul_rn(v, v));
  }
  s = __fadd_rn(s, __shfl_xor(s, 1));
  s = __fadd_rn(s, __shfl_xor(s, 2));
  s = __fadd_rn(s, __shfl_xor(s, 4));
  s = __fadd_rn(s, __shfl_xor(s, 8));
  if (l == 0) dst[g] = s;
}

// ---------------- main: bf16 MFMA approx scores + per-block top-3 keys -------
// Transposed GEMM: C[k_local, n_local] = sum_d E[k,d] * X[n,d];
// biased score = (1+Bk[k]) - 2*C. Tile 128(k) x 256(n); 4 waves, each owns
// a 128x64 sub-tile (acc 8x4). Staging: 12 precomputed (global,LDS) pointer
// pairs; per K-chunk reissued with kc*128 as the instruction's imm offset
// (zero per-chunk address VALU). LDS XOR-swizzle (T2, rule #21) as before.
// Output layout transposed: top2out[n][kb] for coalesced refine reads.
#define STAGE_ALL(KC)                                                          \
  {                                                                            \
    _Pragma("unroll") for (int it = 0; it < 4; ++it)                           \
        __builtin_amdgcn_global_load_lds((as1_cvoid*)egp[it],                  \
                                         (as3_void*)elp[it], 16, (KC)*128, 0); \
    _Pragma("unroll") for (int it = 0; it < 8; ++it)                           \
        __builtin_amdgcn_global_load_lds((as1_cvoid*)xgp[it],                  \
                                         (as3_void*)xlp[it], 16, (KC)*128, 0); \
  }

__global__ __launch_bounds__(256, 2) void score_top2(
    const unsigned short* __restrict__ eb,
    const unsigned short* __restrict__ xb,
    const float* __restrict__ Bk,
    uint4* __restrict__ top2out) {
  __shared__ __align__(16) short Es[128 * 64];
  __shared__ __align__(16) short Xs[256 * 64];
  __shared__ float bks[128];

  const int tid = threadIdx.x;
  // XCD-chunked decode: each XCD owns 16 contiguous 256-col n-panels
  const int bid = blockIdx.x;
  const int xcd = bid & 7;
  const int u = bid >> 3;
  const int nb = xcd * 16 + (u & 15);
  const int kb = u >> 4;
  const int kbase = kb * 128, nbase = nb * 256;
  const int lane = tid & 63;
  const int wid = tid >> 6;
  const int l15 = lane & 15, lhi = lane >> 4;

  if (tid < 128) bks[tid] = Bk[kbase + tid] + 1.0f;   // bias folded here

  // precomputed staging pointer pairs (constant across K-chunks)
  const unsigned short* egp[4]; short* elp[4];
  const unsigned short* xgp[8]; short* xlp[8];
  #pragma unroll
  for (int it = 0; it < 4; ++it) {
    int c = it * 256 + tid;
    int row = c >> 3;
    int col = ((c & 7) ^ (row & 7)) * 8;     // inverse-swizzled global column
    egp[it] = eb + (size_t)(kbase + row) * DIM + col;
    elp[it] = &Es[c * 8];
  }
  #pragma unroll
  for (int it = 0; it < 8; ++it) {
    int c = it * 256 + tid;
    int row = c >> 3;
    int col = ((c & 7) ^ (row & 7)) * 8;
    xgp[it] = xb + (size_t)(nbase + row) * DIM + col;
    xlp[it] = &Xs[c * 8];
  }

  f32x4 acc[8][4];
  #pragma unroll
  for (int i = 0; i < 8; ++i)
    #pragma unroll
    for (int j = 0; j < 4; ++j) acc[i][j] = (f32x4){0.f, 0.f, 0.f, 0.f};

  #pragma unroll
  for (int kc = 0; kc < 4; ++kc) {
    __syncthreads();  // previous chunk's frag reads done
    switch (kc) {     // imm-offset staging (folds after unroll)
      case 0: STAGE_ALL(0); break;
      case 1: STAGE_ALL(1); break;
      case 2: STAGE_ALL(2); break;
      default: STAGE_ALL(3); break;
    }
    __syncthreads();  // drains vmcnt(0): staged data visible
    #pragma unroll
    for (int kk = 0; kk < 2; ++kk) {
      const int pd = (kk * 32 + lhi * 8) ^ ((l15 & 7) << 3);  // swizzled read
      bf16x8 af[8], bfv[4];
      #pragma unroll
      for (int am = 0; am < 8; ++am)
        af[am] = *(const bf16x8*)(&Es[(16 * am + l15) * 64 + pd]);
      #pragma unroll
      for (int bn = 0; bn < 4; ++bn)
        bfv[bn] = *(const bf16x8*)(&Xs[(64 * wid + 16 * bn + l15) * 64 + pd]);
      #pragma unroll
      for (int am = 0; am < 8; ++am)
        #pragma unroll
        for (int bn = 0; bn < 4; ++bn)
          acc[am][bn] = __builtin_amdgcn_mfma_f32_16x16x32_bf16(
              af[am], bfv[bn], acc[am][bn], 0, 0, 0);
    }
  }

  // ---- epilogue: per column, sorted top-3 biased-key triple over 128 codes --
  const int rb = lhi * 4;                      // block-local row base (0..12)
  float bv[32];
  #pragma unroll
  for (int a = 0; a < 8; ++a)
    #pragma unroll
    for (int r = 0; r < 4; ++r) bv[a * 4 + r] = bks[16 * a + rb + r];

  #pragma unroll
  for (int bn = 0; bn < 4; ++bn) {
    unsigned v1 = 0xFFFFFFFFu, v2 = 0xFFFFFFFFu, v3 = 0xFFFFFFFFu;
    #pragma unroll
    for (int a = 0; a < 8; ++a) {
      #pragma unroll
      for (int r = 0; r < 4; ++r) {
        float sc = fmaf(-2.f, acc[a][bn][r], bv[a * 4 + r]);   // positive, monotone bits
        unsigned key = (__float_as_uint(sc) & 0xFFFFFF80u)
                     | (unsigned)(16 * a + rb + r);
        unsigned t1 = umax2(v1, key); v1 = umin2(v1, key);
        unsigned t2 = umax2(v2, t1);  v2 = umin2(v2, t1);
        v3 = umin2(v3, t2);
      }
    }
    // merge sorted triples across the 4 lane-groups (xor 16, 32)
    #pragma unroll
    for (int mm = 16; mm <= 32; mm <<= 1) {
      unsigned o1 = (unsigned)__shfl_xor((int)v1, mm);
      unsigned o2 = (unsigned)__shfl_xor((int)v2, mm);
      unsigned o3 = (unsigned)__shfl_xor((int)v3, mm);
      unsigned z1 = umin2(v1, o1), w1 = umax2(v1, o1);
      unsigned z2 = umin2(v2, o2);
      unsigned z3 = umin2(v3, o3);
      v1 = z1;
      unsigned mx = umax2(w1, z2);
      v2 = umin2(w1, z2);
      v3 = umin2(mx, z3);
    }
    if (lane < 16)
      top2out[(size_t)(nbase + 64 * wid + 16 * bn + lane) * 64 + kb] =
          make_uint4(v1, v2, v3, 0u);
  }
}

// ---------------- refine2: candidate-parallel np-faithful argmin -------------
// Candidate set per row: {i1,i2 of blocks with v<=lim} + full scan of blocks
// with v3<=lim (provably complete). Cooperative dots: 4 candidates per batch,
// 16 lanes each (one L2-latency round per batch); dd via the bit-validated
// np fp32 pipeline; (dd,k) lex-min = np first-min.
__global__ __launch_bounds__(256) void refine2(
    const uint4* __restrict__ top2,
    const float* __restrict__ x,
    const float* __restrict__ e,
    const float* __restrict__ An,
    const float* __restrict__ Bk,
    float* __restrict__ out,
    double* __restrict__ partials) {
  __shared__ float4 xs[4][64];
  __shared__ int cand[4][128];
  __shared__ int fblk[4][64];
  __shared__ double wsum[4];

  const int tid = threadIdx.x;
  const int lane = tid & 63, wid = tid >> 6;
  const int n = blockIdx.x * 4 + wid;   // one wave per row

  float4 xv = ((const float4*)x)[(size_t)n * 64 + lane];
  xs[wid][lane] = xv;

  uint4 t = top2[(size_t)n * 64 + lane];   // coalesced: lane = kblock id
  float fv1 = key2f(t.x), fv2 = key2f(t.y), fv3 = key2f(t.z);
  float m = fv1;
  #pragma unroll
  for (int s = 1; s < 64; s <<= 1) m = fminf(m, __shfl_xor(m, s));
  float lim = m + EPSM;

  unsigned long long b1 = __ballot(fv1 <= lim);
  unsigned long long b2 = __ballot(fv2 <= lim);
  unsigned long long b3 = __ballot(fv3 <= lim);
  unsigned long long ltm = (1ull << lane) - 1ull;
  int c1 = __popcll(b1);
  int ncand = c1 + __popcll(b2);
  if (fv1 <= lim) cand[wid][__popcll(b1 & ltm)] = lane * 128 + (int)(t.x & 127u);
  if (fv2 <= lim) cand[wid][c1 + __popcll(b2 & ltm)] = lane * 128 + (int)(t.y & 127u);
  int nflag = __popcll(b3);
  if (fv3 <= lim) fblk[wid][__popcll(b3 & ltm)] = lane;
  const float A0 = An[n];
  __syncthreads();

  const int l16 = lane & 15;     // d-chunk slot
  const int grp = lane >> 4;     // candidate slot within batch
  float bd = INFINITY; int bi = 0x7FFFFFFF;
  for (int cb = 0; cb < ncand; cb += 4) {
    int ci = cb + grp;
    bool act = ci < ncand;
    int k = act ? cand[wid][ci] : 0;
    const float4* er = (const float4*)e + (size_t)k * 64;
    double d = 0.0;
    #pragma unroll
    for (int tt = 0; tt < 4; ++tt) {
      float4 ev = er[l16 + 16 * tt];
      float4 xf = xs[wid][l16 + 16 * tt];
      d += (double)ev.x * (double)xf.x + (double)ev.y * (double)xf.y
         + (double)ev.z * (double)xf.z + (double)ev.w * (double)xf.w;
    }
    #pragma unroll
    for (int sh = 1; sh < 16; sh <<= 1) d += __shfl_xor(d, sh);
    if (act && l16 == 0) {
      float dd = __fsub_rn(__fadd_rn(A0, Bk[k]), __fmul_rn(2.0f, (float)d));
      if (dd < bd || (dd == bd && k < bi)) { bd = dd; bi = k; }
    }
  }
  // rare exact fallback: blocks whose top-2 is provably insufficient
  for (int f = 0; f < nflag; ++f) {
    int b = fblk[wid][f];
    #pragma unroll
    for (int half = 0; half < 2; ++half) {
      int k = b * 128 + half * 64 + lane;   // all 64 lanes active
      const float4* er = (const float4*)e + (size_t)k * 64;
      double d = 0.0;
      #pragma unroll 4
      for (int j = 0; j < 64; ++j) {
        float4 ev = er[j];
        float4 xf = xs[wid][j];
        d += (double)ev.x * (double)xf.x + (double)ev.y * (double)xf.y
           + (double)ev.z * (double)xf.z + (double)ev.w * (double)xf.w;
      }
      float dd = __fsub_rn(__fadd_rn(A0, Bk[k]), __fmul_rn(2.0f, (float)d));
      if (dd < bd || (dd == bd && k < bi)) { bd = dd; bi = k; }
    }
  }
  // (dd, k) lexicographic min across the wave == numpy first-min
  #pragma unroll
  for (int s = 1; s < 64; s <<= 1) {
    float od = __shfl_xor(bd, s);
    int oi = __shfl_xor(bi, s);
    if (od < bd || (od == bd && oi < bi)) { bd = od; bi = oi; }
  }

  // outputs
  float4 q = ((const float4*)e)[(size_t)bi * 64 + lane];
  ((float4*)out)[(size_t)n * 64 + lane] = q;   // quantized_st == quantized
  double a0 = (double)q.x - (double)xv.x;
  double a1 = (double)q.y - (double)xv.y;
  double a2 = (double)q.z - (double)xv.z;
  double a3 = (double)q.w - (double)xv.w;
  double l = a0 * a0 + a1 * a1 + a2 * a2 + a3 * a3;
  #pragma unroll
  for (int sh = 1; sh < 64; sh <<= 1) l += __shfl_xor(l, sh);
  if (lane == 0) {
    wsum[wid] = l;
    out[(size_t)NTOK * DIM + 1 + n] = (float)bi;   // indices region
  }
  __syncthreads();
  if (tid == 0) partials[blockIdx.x] = wsum[0] + wsum[1] + wsum[2] + wsum[3];
}

// ---------------- finalize: deterministic loss reduction ----------------
__global__ __launch_bounds__(256) void finalize(const double* __restrict__ partials,
                                                float* __restrict__ out) {
  __shared__ double sd[256];
  double s = 0;
  for (int i = threadIdx.x; i < NTOK / 4; i += 256) s += partials[i];
  sd[threadIdx.x] = s;
  __syncthreads();
  for (int st = 128; st > 0; st >>= 1) {
    if (threadIdx.x < st) sd[threadIdx.x] += sd[threadIdx.x + st];
    __syncthreads();
  }
  if (threadIdx.x == 0)
    out[(size_t)NTOK * DIM] = (float)(1.25 * sd[0] / ((double)NTOK * (double)DIM));
}

extern "C" void kernel_launch(void* const* d_in, const int* in_sizes, int n_in,
                              void* d_out, int out_size, void* d_ws, size_t ws_size,
                              hipStream_t stream) {
  const float* x = (const float*)d_in[0];   // [32768, 256]
  const float* e = (const float*)d_in[1];   // [8192, 256]
  float* out = (float*)d_out;

  // workspace layout (~54.7 MB)
  char* w = (char*)d_ws;
  unsigned short* xb = (unsigned short*)(w + 0);            // 16,777,216 B
  unsigned short* eb = (unsigned short*)(w + 16777216);     //  4,194,304 B
  float* An        = (float*)(w + 20971520);                //    131,072 B
  float* Bk        = (float*)(w + 21102592);                //     32,768 B
  uint4* top2      = (uint4*)(w + 21135360);                // 33,554,432 B
  double* partials = (double*)(w + 54689792);               //     65,536 B

  cast_bf16_k<<<(NTOK * DIM / 8 + 255) / 256, 256, 0, stream>>>(x, xb, NTOK * DIM / 8);
  cast_bf16_k<<<(KEMB * DIM / 8 + 255) / 256, 256, 0, stream>>>(e, eb, KEMB * DIM / 8);
  rowsq_np<<<NTOK / 16, 256, 0, stream>>>(x, An, NTOK);
  rowsq_np<<<KEMB / 16, 256, 0, stream>>>(e, Bk, KEMB);

  score_top2<<<8192, 256, 0, stream>>>(eb, xb, Bk, top2);

  refine2<<<NTOK / 4, 256, 0, stream>>>(top2, x, e, An, Bk, out, partials);
  finalize<<<1, 256, 0, stream>>>(partials, out);
}

// Round 14
// 276.770 us; speedup vs baseline: 103.8325x; 103.8325x over previous
//
#include <hip/hip_runtime.h>
#include <hip/hip_bf16.h>

#define NTOK 32768   // input rows
#define KEMB 8192    // embedding codes
#define DIM  256     // feature dim
#define EPSM 1e-3f   // gate margin: worst-case |s_hat - np_dd| ~1.8e-4 incl key trunc

typedef __attribute__((ext_vector_type(8))) short bf16x8;
typedef __attribute__((ext_vector_type(4))) float f32x4;
typedef __attribute__((ext_vector_type(8))) unsigned short ushort8;

typedef __attribute__((address_space(3))) void as3_void;
typedef __attribute__((address_space(1))) const void as1_cvoid;

__device__ __forceinline__ void gload_lds16(const void* g, void* l) {
  __builtin_amdgcn_global_load_lds((as1_cvoid*)g, (as3_void*)l, 16, 0, 0);
}

__device__ __forceinline__ unsigned short f2bf(float f) {
  unsigned int u = __float_as_uint(f);
  unsigned int r = (u + 0x7FFFu + ((u >> 16) & 1u)) >> 16;
  return (unsigned short)r;
}

__device__ __forceinline__ unsigned umin2(unsigned a, unsigned b) { return a < b ? a : b; }
__device__ __forceinline__ unsigned umax2(unsigned a, unsigned b) { return a > b ? a : b; }

// biased-key scheme: all scores stored as (score + 1.0) > 0, so the raw fp32
// bit pattern is order-preserving. Low 7 bits carry the block-local index.
__device__ __forceinline__ float key2f(unsigned k) {
  return __uint_as_float(k & 0xFFFFFF80u) - 1.0f;
}

// ---------------- prep: fp32 -> bf16 copies ----------------
__global__ __launch_bounds__(256) void cast_bf16_k(const float* __restrict__ src,
                                                   unsigned short* __restrict__ dst,
                                                   int n8) {
  int i = blockIdx.x * 256 + threadIdx.x;
  if (i >= n8) return;
  const float4* s4 = (const float4*)src;
  float4 a = s4[2 * i], b = s4[2 * i + 1];
  ushort8 r;
  r[0] = f2bf(a.x); r[1] = f2bf(a.y); r[2] = f2bf(a.z); r[3] = f2bf(a.w);
  r[4] = f2bf(b.x); r[5] = f2bf(b.y); r[6] = f2bf(b.z); r[7] = f2bf(b.w);
  ((ushort8*)dst)[i] = r;
}

// ---------------- numpy-pairwise fp32 row sum of squares (validated r8) ------
__global__ __launch_bounds__(256) void rowsq_np(const float* __restrict__ src,
                                                float* __restrict__ dst,
                                                int nrows) {
  int g = (blockIdx.x * 256 + threadIdx.x) >> 4;   // row id
  if (g >= nrows) return;
  int l = threadIdx.x & 15;
  int j = l & 7, half = l >> 3;
  const float* row = src + (size_t)g * DIM + half * 128 + j;
  float s = 0.f;
  #pragma unroll
  for (int i = 0; i < 16; ++i) {
    float v = row[8 * i];
    s = __fadd_rn(s, __fmul_rn(v, v));
  }
  s = __fadd_rn(s, __shfl_xor(s, 1));
  s = __fadd_rn(s, __shfl_xor(s, 2));
  s = __fadd_rn(s, __shfl_xor(s, 4));
  s = __fadd_rn(s, __shfl_xor(s, 8));
  if (l == 0) dst[g] = s;
}

// ---------------- main: bf16 MFMA approx scores + per-block top-3 keys -------
// Transposed GEMM: C[k_local, n_local] = sum_d E[k,d] * X[n,d];
// biased score = (1+Bk[k]) - 2*C. Tile 128(k) x 256(n); 4 waves, each owns
// a 128x64 sub-tile (acc 8x4). Staging: r12's proven per-chunk address form
// (offset=0 global_load_lds — imm-offset variant from r13 silently corrupted
// the staged tiles; reverted). LDS XOR-swizzle (T2, rule #21) as before.
// Output layout transposed: top2out[n][kb] for coalesced refine reads.
__global__ __launch_bounds__(256, 2) void score_top2(
    const unsigned short* __restrict__ eb,
    const unsigned short* __restrict__ xb,
    const float* __restrict__ Bk,
    uint4* __restrict__ top2out) {
  __shared__ __align__(16) short Es[128 * 64];
  __shared__ __align__(16) short Xs[256 * 64];
  __shared__ float bks[128];

  const int tid = threadIdx.x;
  // XCD-chunked decode: each XCD owns 16 contiguous 256-col n-panels
  const int bid = blockIdx.x;
  const int xcd = bid & 7;
  const int u = bid >> 3;
  const int nb = xcd * 16 + (u & 15);
  const int kb = u >> 4;
  const int kbase = kb * 128, nbase = nb * 256;
  const int lane = tid & 63;
  const int wid = tid >> 6;
  const int l15 = lane & 15, lhi = lane >> 4;

  if (tid < 128) bks[tid] = Bk[kbase + tid] + 1.0f;   // bias folded here

  f32x4 acc[8][4];
  #pragma unroll
  for (int i = 0; i < 8; ++i)
    #pragma unroll
    for (int j = 0; j < 4; ++j) acc[i][j] = (f32x4){0.f, 0.f, 0.f, 0.f};

  #pragma unroll
  for (int kc = 0; kc < 4; ++kc) {
    __syncthreads();  // previous chunk's frag reads done
    #pragma unroll
    for (int it = 0; it < 4; ++it) {
      int c = it * 256 + tid;                  // E chunks 0..1023
      int row = c >> 3;
      int col = ((c & 7) ^ (row & 7)) * 8;     // inverse-swizzled global column
      gload_lds16(eb + (size_t)(kbase + row) * DIM + kc * 64 + col, &Es[c * 8]);
    }
    #pragma unroll
    for (int it = 0; it < 8; ++it) {
      int c = it * 256 + tid;                  // X chunks 0..2047
      int row = c >> 3;
      int col = ((c & 7) ^ (row & 7)) * 8;
      gload_lds16(xb + (size_t)(nbase + row) * DIM + kc * 64 + col, &Xs[c * 8]);
    }
    __syncthreads();  // drains vmcnt(0): staged data visible
    #pragma unroll
    for (int kk = 0; kk < 2; ++kk) {
      const int pd = (kk * 32 + lhi * 8) ^ ((l15 & 7) << 3);  // swizzled read
      bf16x8 af[8], bfv[4];
      #pragma unroll
      for (int am = 0; am < 8; ++am)
        af[am] = *(const bf16x8*)(&Es[(16 * am + l15) * 64 + pd]);
      #pragma unroll
      for (int bn = 0; bn < 4; ++bn)
        bfv[bn] = *(const bf16x8*)(&Xs[(64 * wid + 16 * bn + l15) * 64 + pd]);
      #pragma unroll
      for (int am = 0; am < 8; ++am)
        #pragma unroll
        for (int bn = 0; bn < 4; ++bn)
          acc[am][bn] = __builtin_amdgcn_mfma_f32_16x16x32_bf16(
              af[am], bfv[bn], acc[am][bn], 0, 0, 0);
    }
  }

  // ---- epilogue: per column, sorted top-3 biased-key triple over 128 codes --
  const int rb = lhi * 4;                      // block-local row base (0..12)
  float bv[32];
  #pragma unroll
  for (int a = 0; a < 8; ++a)
    #pragma unroll
    for (int r = 0; r < 4; ++r) bv[a * 4 + r] = bks[16 * a + rb + r];

  #pragma unroll
  for (int bn = 0; bn < 4; ++bn) {
    unsigned v1 = 0xFFFFFFFFu, v2 = 0xFFFFFFFFu, v3 = 0xFFFFFFFFu;
    #pragma unroll
    for (int a = 0; a < 8; ++a) {
      #pragma unroll
      for (int r = 0; r < 4; ++r) {
        float sc = fmaf(-2.f, acc[a][bn][r], bv[a * 4 + r]);   // positive, monotone bits
        unsigned key = (__float_as_uint(sc) & 0xFFFFFF80u)
                     | (unsigned)(16 * a + rb + r);
        unsigned t1 = umax2(v1, key); v1 = umin2(v1, key);
        unsigned t2 = umax2(v2, t1);  v2 = umin2(v2, t1);
        v3 = umin2(v3, t2);
      }
    }
    // merge sorted triples across the 4 lane-groups (xor 16, 32)
    #pragma unroll
    for (int mm = 16; mm <= 32; mm <<= 1) {
      unsigned o1 = (unsigned)__shfl_xor((int)v1, mm);
      unsigned o2 = (unsigned)__shfl_xor((int)v2, mm);
      unsigned o3 = (unsigned)__shfl_xor((int)v3, mm);
      unsigned z1 = umin2(v1, o1), w1 = umax2(v1, o1);
      unsigned z2 = umin2(v2, o2);
      unsigned z3 = umin2(v3, o3);
      v1 = z1;
      unsigned mx = umax2(w1, z2);
      v2 = umin2(w1, z2);
      v3 = umin2(mx, z3);
    }
    if (lane < 16)
      top2out[(size_t)(nbase + 64 * wid + 16 * bn + lane) * 64 + kb] =
          make_uint4(v1, v2, v3, 0u);
  }
}

// ---------------- refine2: candidate-parallel np-faithful argmin -------------
// Candidate set per row: {i1,i2 of blocks with v<=lim} + full scan of blocks
// with v3<=lim (provably complete). Cooperative dots: 4 candidates per batch,
// 16 lanes each (one L2-latency round per batch); dd via the bit-validated
// np fp32 pipeline; (dd,k) lex-min = np first-min.
__global__ __launch_bounds__(256) void refine2(
    const uint4* __restrict__ top2,
    const float* __restrict__ x,
    const float* __restrict__ e,
    const float* __restrict__ An,
    const float* __restrict__ Bk,
    float* __restrict__ out,
    double* __restrict__ partials) {
  __shared__ float4 xs[4][64];
  __shared__ int cand[4][128];
  __shared__ int fblk[4][64];
  __shared__ double wsum[4];

  const int tid = threadIdx.x;
  const int lane = tid & 63, wid = tid >> 6;
  const int n = blockIdx.x * 4 + wid;   // one wave per row

  float4 xv = ((const float4*)x)[(size_t)n * 64 + lane];
  xs[wid][lane] = xv;

  uint4 t = top2[(size_t)n * 64 + lane];   // coalesced: lane = kblock id
  float fv1 = key2f(t.x), fv2 = key2f(t.y), fv3 = key2f(t.z);
  float m = fv1;
  #pragma unroll
  for (int s = 1; s < 64; s <<= 1) m = fminf(m, __shfl_xor(m, s));
  float lim = m + EPSM;

  unsigned long long b1 = __ballot(fv1 <= lim);
  unsigned long long b2 = __ballot(fv2 <= lim);
  unsigned long long b3 = __ballot(fv3 <= lim);
  unsigned long long ltm = (1ull << lane) - 1ull;
  int c1 = __popcll(b1);
  int ncand = c1 + __popcll(b2);
  if (fv1 <= lim) cand[wid][__popcll(b1 & ltm)] = lane * 128 + (int)(t.x & 127u);
  if (fv2 <= lim) cand[wid][c1 + __popcll(b2 & ltm)] = lane * 128 + (int)(t.y & 127u);
  int nflag = __popcll(b3);
  if (fv3 <= lim) fblk[wid][__popcll(b3 & ltm)] = lane;
  const float A0 = An[n];
  __syncthreads();

  const int l16 = lane & 15;     // d-chunk slot
  const int grp = lane >> 4;     // candidate slot within batch
  float bd = INFINITY; int bi = 0x7FFFFFFF;
  for (int cb = 0; cb < ncand; cb += 4) {
    int ci = cb + grp;
    bool act = ci < ncand;
    int k = act ? cand[wid][ci] : 0;
    const float4* er = (const float4*)e + (size_t)k * 64;
    double d = 0.0;
    #pragma unroll
    for (int tt = 0; tt < 4; ++tt) {
      float4 ev = er[l16 + 16 * tt];
      float4 xf = xs[wid][l16 + 16 * tt];
      d += (double)ev.x * (double)xf.x + (double)ev.y * (double)xf.y
         + (double)ev.z * (double)xf.z + (double)ev.w * (double)xf.w;
    }
    #pragma unroll
    for (int sh = 1; sh < 16; sh <<= 1) d += __shfl_xor(d, sh);
    if (act && l16 == 0) {
      float dd = __fsub_rn(__fadd_rn(A0, Bk[k]), __fmul_rn(2.0f, (float)d));
      if (dd < bd || (dd == bd && k < bi)) { bd = dd; bi = k; }
    }
  }
  // rare exact fallback: blocks whose top-2 is provably insufficient
  for (int f = 0; f < nflag; ++f) {
    int b = fblk[wid][f];
    #pragma unroll
    for (int half = 0; half < 2; ++half) {
      int k = b * 128 + half * 64 + lane;   // all 64 lanes active
      const float4* er = (const float4*)e + (size_t)k * 64;
      double d = 0.0;
      #pragma unroll 4
      for (int j = 0; j < 64; ++j) {
        float4 ev = er[j];
        float4 xf = xs[wid][j];
        d += (double)ev.x * (double)xf.x + (double)ev.y * (double)xf.y
           + (double)ev.z * (double)xf.z + (double)ev.w * (double)xf.w;
      }
      float dd = __fsub_rn(__fadd_rn(A0, Bk[k]), __fmul_rn(2.0f, (float)d));
      if (dd < bd || (dd == bd && k < bi)) { bd = dd; bi = k; }
    }
  }
  // (dd, k) lexicographic min across the wave == numpy first-min
  #pragma unroll
  for (int s = 1; s < 64; s <<= 1) {
    float od = __shfl_xor(bd, s);
    int oi = __shfl_xor(bi, s);
    if (od < bd || (od == bd && oi < bi)) { bd = od; bi = oi; }
  }

  // outputs
  float4 q = ((const float4*)e)[(size_t)bi * 64 + lane];
  ((float4*)out)[(size_t)n * 64 + lane] = q;   // quantized_st == quantized
  double a0 = (double)q.x - (double)xv.x;
  double a1 = (double)q.y - (double)xv.y;
  double a2 = (double)q.z - (double)xv.z;
  double a3 = (double)q.w - (double)xv.w;
  double l = a0 * a0 + a1 * a1 + a2 * a2 + a3 * a3;
  #pragma unroll
  for (int sh = 1; sh < 64; sh <<= 1) l += __shfl_xor(l, sh);
  if (lane == 0) {
    wsum[wid] = l;
    out[(size_t)NTOK * DIM + 1 + n] = (float)bi;   // indices region
  }
  __syncthreads();
  if (tid == 0) partials[blockIdx.x] = wsum[0] + wsum[1] + wsum[2] + wsum[3];
}

// ---------------- finalize: deterministic loss reduction ----------------
__global__ __launch_bounds__(256) void finalize(const double* __restrict__ partials,
                                                float* __restrict__ out) {
  __shared__ double sd[256];
  double s = 0;
  for (int i = threadIdx.x; i < NTOK / 4; i += 256) s += partials[i];
  sd[threadIdx.x] = s;
  __syncthreads();
  for (int st = 128; st > 0; st >>= 1) {
    if (threadIdx.x < st) sd[threadIdx.x] += sd[threadIdx.x + st];
    __syncthreads();
  }
  if (threadIdx.x == 0)
    out[(size_t)NTOK * DIM] = (float)(1.25 * sd[0] / ((double)NTOK * (double)DIM));
}

extern "C" void kernel_launch(void* const* d_in, const int* in_sizes, int n_in,
                              void* d_out, int out_size, void* d_ws, size_t ws_size,
                              hipStream_t stream) {
  const float* x = (const float*)d_in[0];   // [32768, 256]
  const float* e = (const float*)d_in[1];   // [8192, 256]
  float* out = (float*)d_out;

  // workspace layout (~54.7 MB)
  char* w = (char*)d_ws;
  unsigned short* xb = (unsigned short*)(w + 0);            // 16,777,216 B
  unsigned short* eb = (unsigned short*)(w + 16777216);     //  4,194,304 B
  float* An        = (float*)(w + 20971520);                //    131,072 B
  float* Bk        = (float*)(w + 21102592);                //     32,768 B
  uint4* top2      = (uint4*)(w + 21135360);                // 33,554,432 B
  double* partials = (double*)(w + 54689792);               //     65,536 B

  cast_bf16_k<<<(NTOK * DIM / 8 + 255) / 256, 256, 0, stream>>>(x, xb, NTOK * DIM / 8);
  cast_bf16_k<<<(KEMB * DIM / 8 + 255) / 256, 256, 0, stream>>>(e, eb, KEMB * DIM / 8);
  rowsq_np<<<NTOK / 16, 256, 0, stream>>>(x, An, NTOK);
  rowsq_np<<<KEMB / 16, 256, 0, stream>>>(e, Bk, KEMB);

  score_top2<<<8192, 256, 0, stream>>>(eb, xb, Bk, top2);

  refine2<<<NTOK / 4, 256, 0, stream>>>(top2, x, e, An, Bk, out, partials);
  finalize<<<1, 256, 0, stream>>>(partials, out);
}